// Round 7
// baseline (115.702 us; speedup 1.0000x reference)
//
#include <hip/hip_runtime.h>

// IntraSentenceAttention, single-kernel MFMA bf16.
// out[b,i,:] = m_i * sum_j e_ij x[b,j,:] / (sum_j e_ij + EPS)
//   e_ij = exp(dot(x_i,x_j) + min(i-j,10)) * m_j
// B=32, T=1024, D=128. Scores <= ~12.3 -> no online rescale needed.
//
// wave = (i-half h, j-parity p): 32 i-rows per wave, 8 j-tiles per parity;
// every LDS A-read (Kb stage 1, KTb stage 2) feeds 2 MFMAs (ig = 0,1).
// Stage-2 B-frags go through shared Pb (round-5-verified layout); parities
// alternate Pb use, separated by the per-iteration barrier.
// Double-buffered Kb/KTb staging, 1 barrier/tile; buffer index == tile parity.

typedef __bf16 bf16x8 __attribute__((ext_vector_type(8)));
typedef __bf16 bf16x4 __attribute__((ext_vector_type(4)));
typedef float  f32x4  __attribute__((ext_vector_type(4)));

constexpr int Tn = 1024;
constexpr int Dn = 128;
constexpr int BM = 64;
constexpr int BN = 64;
constexpr int NT = Tn / BN;      // 16 j-tiles
constexpr float EPSF = 1e-7f;

// KTb chunk swizzle (3 bits + d-bit6 fold)
__device__ __forceinline__ int ktf3(int d) {
    return (((d >> 3) ^ d) & 7) ^ (((d >> 6) & 1) << 1);
}

__global__ __launch_bounds__(256, 2)
void attn_mfma(const float* __restrict__ x, const int* __restrict__ mask,
               float* __restrict__ out) {
    __shared__ __align__(16) __bf16 Kb[2][64 * 128];    // 32 KB [j][d], chunk c at c^(j&15)
    __shared__ __align__(16) __bf16 KTb[2][128 * 64];   // 32 KB [d][j], chunk c at c^ktf3(d)
    __shared__ __align__(16) __bf16 Pb[64 * 64];        // 8 KB  [i][j], chunk c at c^(i&7)
    __shared__ __align__(16) float mb[2][64];           // mask bias (0 / -1e5)

    const int t = threadIdx.x, w = t >> 6, l = t & 63;
    const int m = l & 15, quad = l >> 4;
    const int h = w & 1, p = w >> 1;     // i-half, j-parity
    const int bid = blockIdx.x;
    const int b = bid & 31, i0 = (bid >> 5) * BM;   // bid%8==b%8: XCD L2 affinity
    const float* xb = x + (size_t)b * Tn * Dn;

    // ---- Q fragments, two 16-row groups (i = i0+h*32+ig*16+m), held all kernel ----
    bf16x8 aq[2][4];
    #pragma unroll
    for (int ig = 0; ig < 2; ++ig) {
        const float* qrow = xb + (size_t)(i0 + h * 32 + ig * 16 + m) * Dn + quad * 8;
        #pragma unroll
        for (int kt = 0; kt < 4; ++kt) {
            float4 a = *(const float4*)(qrow + kt * 32);
            float4 c = *(const float4*)(qrow + kt * 32 + 4);
            bf16x8 v;
            v[0]=(__bf16)a.x; v[1]=(__bf16)a.y; v[2]=(__bf16)a.z; v[3]=(__bf16)a.w;
            v[4]=(__bf16)c.x; v[5]=(__bf16)c.y; v[6]=(__bf16)c.z; v[7]=(__bf16)c.w;
            aq[ig][kt] = v;
        }
    }

    // staging: thread owns rows rg*4..+3, d-chunk c8 (8 floats)
    const int rg = t >> 4, c8 = t & 15;
    float4 pfa[4], pfb[4];
    float mreg = 0.f;

    auto load_tile = [&](int j0) {
        #pragma unroll
        for (int k = 0; k < 4; ++k) {
            const float* pp = xb + (size_t)(j0 + rg * 4 + k) * Dn + c8 * 8;
            pfa[k] = *(const float4*)pp;
            pfb[k] = *(const float4*)(pp + 4);
        }
        if (t < 64) mreg = (mask[b * Tn + j0 + t] != 0) ? 0.f : -1e5f;
    };

    auto commit = [&](int bs) {
        bf16x8 vv[4];
        #pragma unroll
        for (int k = 0; k < 4; ++k) {
            bf16x8 v;
            v[0]=(__bf16)pfa[k].x; v[1]=(__bf16)pfa[k].y;
            v[2]=(__bf16)pfa[k].z; v[3]=(__bf16)pfa[k].w;
            v[4]=(__bf16)pfb[k].x; v[5]=(__bf16)pfb[k].y;
            v[6]=(__bf16)pfb[k].z; v[7]=(__bf16)pfb[k].w;
            vv[k] = v;
            const int r = rg * 4 + k;
            *(bf16x8*)(&Kb[bs][r * 128 + ((c8 ^ (r & 15)) * 8)]) = v;   // b128
        }
        #pragma unroll
        for (int q = 0; q < 8; ++q) {       // transpose: b64 j-runs
            const int d = c8 * 8 + q;
            bf16x4 pj;
            pj[0]=vv[0][q]; pj[1]=vv[1][q]; pj[2]=vv[2][q]; pj[3]=vv[3][q];
            *(bf16x4*)(&KTb[bs][d * 64 + (((rg >> 1) ^ ktf3(d)) * 8) + ((rg & 1) * 4)]) = pj;
        }
        if (t < 64) mb[bs][t] = mreg;
    };

    load_tile(0);
    commit(0);
    load_tile(BN);

    f32x4 acc[2][8];
    #pragma unroll
    for (int ig = 0; ig < 2; ++ig)
        #pragma unroll
        for (int n2 = 0; n2 < 8; ++n2) acc[ig][n2] = (f32x4){0.f,0.f,0.f,0.f};
    float dsum[2] = {0.f, 0.f};
    const float fi0 = (float)(i0 + h * 32 + m);

    for (int jt = 0; jt < NT; ++jt) {
        const int bs = jt & 1, j0 = jt * BN;
        __syncthreads();                 // buf[bs]+Pb handoff barrier
        commit(bs ^ 1);                  // tile jt+1 -> other buffer
        const int jl = (jt + 2 < NT) ? (jt + 2) : (NT - 1);
        load_tile(jl * BN);              // prefetch tile jt+2

        if (bs == p) {                   // this wave's parity: 32 i x 64 j
            // ---- stage 1: S^T = K*Q^T; every A-read feeds both ig MFMAs ----
            #pragma unroll
            for (int nt = 0; nt < 4; ++nt) {
                const int arow = nt * 16 + m;
                f32x4 cs0 = {0.f,0.f,0.f,0.f}, cs1 = {0.f,0.f,0.f,0.f};
                #pragma unroll
                for (int kt = 0; kt < 4; ++kt) {
                    bf16x8 av = *(const bf16x8*)(&Kb[bs][arow * 128 +
                                   (((kt * 4 + quad) ^ (arow & 15)) * 8)]);
                    cs0 = __builtin_amdgcn_mfma_f32_16x16x32_bf16(av, aq[0][kt], cs0, 0,0,0);
                    cs1 = __builtin_amdgcn_mfma_f32_16x16x32_bf16(av, aq[1][kt], cs1, 0,0,0);
                }
                // C layout: col = i = m (fixed), row = j = nt*16 + quad*4 + r
                float4 m4 = *(const float4*)&mb[bs][nt * 16 + quad * 4];
                const float jb = (float)(j0 + nt * 16 + quad * 4);
                const int jc = nt * 2 + (quad >> 1);       // Pb 8-elem chunk
                #pragma unroll
                for (int ig = 0; ig < 2; ++ig) {
                    const f32x4 cs = ig ? cs1 : cs0;
                    const float base = fi0 + (float)(ig * 16) - jb;
                    bf16x4 pv;
                    #pragma unroll
                    for (int r = 0; r < 4; ++r) {
                        float e = __expf(cs[r] + fminf(base - (float)r, 10.f)
                                         + ((const float*)&m4)[r]);
                        dsum[ig] += e;
                        pv[r] = (__bf16)e;
                    }
                    const int prow = h * 32 + ig * 16 + m;
                    *(bf16x4*)(&Pb[prow * 64 + ((jc ^ (m & 7)) * 8) + (quad & 1) * 4]) = pv;
                }
            }
            // ---- stage-2 B-frags from Pb (wave-private rows, no barrier) ----
            bf16x8 ap[2][2];
            #pragma unroll
            for (int ig = 0; ig < 2; ++ig) {
                const int prow = h * 32 + ig * 16 + m;
                #pragma unroll
                for (int k2 = 0; k2 < 2; ++k2)
                    ap[ig][k2] = *(const bf16x8*)(&Pb[prow * 64 +
                                     (((k2 * 4 + quad) ^ (m & 7)) * 8)]);
            }
            // ---- stage 2: O^T += K^T * P^T; every A-read feeds both ig ----
            #pragma unroll
            for (int n2 = 0; n2 < 8; ++n2) {
                const int drow = n2 * 16 + m;
                #pragma unroll
                for (int k2 = 0; k2 < 2; ++k2) {
                    bf16x8 av = *(const bf16x8*)(&KTb[bs][drow * 64 +
                                   (((k2 * 4 + quad) ^ ktf3(drow)) * 8)]);
                    acc[0][n2] = __builtin_amdgcn_mfma_f32_16x16x32_bf16(av, ap[0][k2], acc[0][n2], 0,0,0);
                    acc[1][n2] = __builtin_amdgcn_mfma_f32_16x16x32_bf16(av, ap[1][k2], acc[1][n2], 0,0,0);
                }
            }
        }
    }

    // ---- epilogue: combine parity partners, normalize, store ----
    #pragma unroll
    for (int ig = 0; ig < 2; ++ig) {
        dsum[ig] += __shfl_xor(dsum[ig], 16);
        dsum[ig] += __shfl_xor(dsum[ig], 32);
    }
    __syncthreads();                     // all compute done; bufs reusable
    float* exf = (float*)&Kb[h][0];      // 16 KB exchange region per i-half
    float* dxf = (float*)&KTb[h][0];
    if (p == 1) {
        #pragma unroll
        for (int ig = 0; ig < 2; ++ig) {
            #pragma unroll
            for (int n2 = 0; n2 < 8; ++n2)
                *(f32x4*)&exf[(ig * 8 + n2) * 256 + l * 4] = acc[ig][n2];
            dxf[ig * 64 + l] = dsum[ig];
        }
    }
    __syncthreads();
    if (p == 0) {
        #pragma unroll
        for (int ig = 0; ig < 2; ++ig) {
            #pragma unroll
            for (int n2 = 0; n2 < 8; ++n2)
                acc[ig][n2] += *(const f32x4*)&exf[(ig * 8 + n2) * 256 + l * 4];
            const float dtot = dsum[ig] + dxf[ig * 64 + l];
            const int i = i0 + h * 32 + ig * 16 + m;
            const float mi = (mask[b * Tn + i] != 0) ? 1.f : 0.f;
            const float inv = mi / (dtot + EPSF);
            float* orow = out + (size_t)(b * Tn + i) * Dn;
            #pragma unroll
            for (int n2 = 0; n2 < 8; ++n2) {
                float4 o;
                o.x = acc[ig][n2][0] * inv; o.y = acc[ig][n2][1] * inv;
                o.z = acc[ig][n2][2] * inv; o.w = acc[ig][n2][3] * inv;
                *(float4*)(orow + n2 * 16 + quad * 4) = o;
            }
        }
    }
}

// ============================ launch ============================
extern "C" void kernel_launch(void* const* d_in, const int* in_sizes, int n_in,
                              void* d_out, int out_size, void* d_ws, size_t ws_size,
                              hipStream_t stream) {
    const float* x    = (const float*)d_in[0];
    const int*   mask = (const int*)d_in[1];
    float*       out  = (float*)d_out;
    const int B = in_sizes[1] / Tn;          // 32
    const int nblocks = B * (Tn / BM);       // 512
    attn_mfma<<<nblocks, 256, 0, stream>>>(x, mask, out);
}

// Round 8
// 101.122 us; speedup vs baseline: 1.1442x; 1.1442x over previous
//
#include <hip/hip_runtime.h>

// IntraSentenceAttention, MFMA bf16 + workspace pre-pass + global_load_lds.
// out[b,i,:] = m_i * sum_j e_ij x[b,j,:] / (sum_j e_ij + EPS)
//   e_ij = exp(dot(x_i,x_j) + min(i-j,10)) * m_j
// B=32, T=1024, D=128. Scores <= ~12.3 -> no online rescale needed.
//
// Key facts learned: harness poisons d_ws EVERY timed iter (268 MB ~ 45 us)
// whether or not we use it -> using d_ws is free. So: prep converts x to
// bf16 (row-major Xb + transposed XbT) in ws; attn stages K/KT tiles via
// __builtin_amdgcn_global_load_lds width=16 (no staging VGPR/VALU/DS-writes).
// Swizzled LDS layouts preserved by permuting the per-lane GLOBAL source
// (LDS dest is mandated base + lane*16; swizzle folded into source chunk).
// Round-5 compute structure (all 4 waves compute every tile, 1 barrier/tile,
// wave-private Pb round-trip) - best measured structure (49 us) - minus its
// staging overhead.

typedef __bf16 bf16x8 __attribute__((ext_vector_type(8)));
typedef __bf16 bf16x4 __attribute__((ext_vector_type(4)));
typedef float  f32x4  __attribute__((ext_vector_type(4)));

typedef const __attribute__((address_space(1))) void* gptr_t;
typedef __attribute__((address_space(3))) void* lptr_t;

constexpr int Tn = 1024;
constexpr int Dn = 128;
constexpr int BM = 64;
constexpr int BN = 64;
constexpr int NT = Tn / BN;      // 16 j-tiles
constexpr float EPSF = 1e-7f;

// ==================== prep: x fp32 -> Xb bf16, XbT bf16 ====================
// grid (Tn/64, B), 256 threads. tile[64][129]: +1 pad breaks column-read
// conflicts; 129 covers full 128-d rows (round-3's [65] overflow bug fixed).
__global__ __launch_bounds__(256)
void prep(const float* __restrict__ x, __bf16* __restrict__ Xb,
          __bf16* __restrict__ XbT) {
    __shared__ float tile[64][129];
    const int b = blockIdx.y, t0 = blockIdx.x * 64, t = threadIdx.x;
    #pragma unroll
    for (int k = 0; k < 8; ++k) {
        int cid = t + k * 256;                 // 2048 units: 64 rows x 32 f4-chunks
        int r = cid >> 5, c4 = cid & 31;
        float4 v = *(const float4*)(x + (size_t)(b * Tn + t0 + r) * Dn + c4 * 4);
        bf16x4 bv;
        bv[0] = (__bf16)v.x; bv[1] = (__bf16)v.y; bv[2] = (__bf16)v.z; bv[3] = (__bf16)v.w;
        *(bf16x4*)(Xb + (size_t)(b * Tn + t0 + r) * Dn + c4 * 4) = bv;
        *(float4*)&tile[r][c4 * 4] = v;
    }
    __syncthreads();
    #pragma unroll
    for (int k = 0; k < 2; ++k) {
        int cid = t + k * 256;                 // 512 units: 128 d x 4 t-chunks(16)
        int dd = cid >> 2, tq = cid & 3;
        bf16x8 v0, v1;
        #pragma unroll
        for (int j = 0; j < 8; ++j) v0[j] = (__bf16)tile[tq * 16 + j][dd];
        #pragma unroll
        for (int j = 0; j < 8; ++j) v1[j] = (__bf16)tile[tq * 16 + 8 + j][dd];
        __bf16* o = XbT + (size_t)(b * Dn + dd) * Tn + t0 + tq * 16;
        *(bf16x8*)o = v0;
        *(bf16x8*)(o + 8) = v1;
    }
}

// ============================ main MFMA kernel ============================
// LDS: Kb [j(64)][d(128)]: 16B-chunk slot s of row r holds chunk s^(r&15)
//      KTb[d(128)][j(64)]: slot s of row d holds chunk s^(d&7)
//      Pb [i(64)][j(64)] : slot s of row i at s^(i&7)  (wave-private rows)
__global__ __launch_bounds__(256, 2)
void attn_mfma(const __bf16* __restrict__ Xb, const __bf16* __restrict__ XbT,
               const int* __restrict__ mask, float* __restrict__ out) {
    __shared__ __align__(16) __bf16 Kb[2][64 * 128];    // 32 KB
    __shared__ __align__(16) __bf16 KTb[2][128 * 64];   // 32 KB
    __shared__ __align__(16) __bf16 Pb[64 * 64];        // 8 KB
    __shared__ __align__(16) float mbias[Tn];           // 4 KB

    const int t = threadIdx.x, w = t >> 6, l = t & 63;
    const int m = l & 15, quad = l >> 4;
    const int bid = blockIdx.x;
    const int b = bid & 31, i0 = (bid >> 5) * BM;   // bid%8==b%8: XCD L2 affinity
    const __bf16* xb  = Xb  + (size_t)b * Tn * Dn;
    const __bf16* xtb = XbT + (size_t)b * Dn * Tn;

    // mask bias for all 1024 j, once
    for (int k = t; k < Tn; k += 256)
        mbias[k] = (mask[b * Tn + k] != 0) ? 0.f : -1e5f;

    // Q fragments in registers all kernel: Q[i0+16w+m][kt*32+quad*8+j]
    bf16x8 aq[4];
    {
        const __bf16* qrow = xb + (size_t)(i0 + 16 * w + m) * Dn + quad * 8;
        #pragma unroll
        for (int kt = 0; kt < 4; ++kt) aq[kt] = *(const bf16x8*)(qrow + kt * 32);
    }

    // DMA one 64-row tile into buffers bs (wave w covers its quarter).
    // Kb call k: lane i -> row k*4 + (i>>4), slot i&15, source chunk slot^(row&15)
    // KTb call k: lane i -> d-row k*8 + (i>>3), slot i&7, source chunk slot^(d&7)
    auto dma_tile = [&](int j0, int bs) {
        #pragma unroll
        for (int q = 0; q < 4; ++q) {
            const int k = w * 4 + q;
            const int rl = k * 4 + (l >> 4);
            const int c  = (l & 15) ^ (rl & 15);
            const __bf16* g = xb + (size_t)(j0 + rl) * Dn + c * 8;
            __builtin_amdgcn_global_load_lds((gptr_t)g, (lptr_t)(&Kb[bs][k * 512]),
                                             16, 0, 0);
        }
        #pragma unroll
        for (int q = 0; q < 4; ++q) {
            const int k = w * 4 + q;
            const int d = k * 8 + (l >> 3);
            const int c = (l & 7) ^ (d & 7);
            const __bf16* g = xtb + (size_t)d * Tn + j0 + c * 8;
            __builtin_amdgcn_global_load_lds((gptr_t)g, (lptr_t)(&KTb[bs][k * 512]),
                                             16, 0, 0);
        }
    };

    dma_tile(0, 0);

    f32x4 acc[8];
    #pragma unroll
    for (int n2 = 0; n2 < 8; ++n2) acc[n2] = (f32x4){0.f, 0.f, 0.f, 0.f};
    float dsum = 0.f;                        // den partial for i = i0+16w+m
    const float fi = (float)(i0 + 16 * w + m);

    __syncthreads();   // tile 0 DMA drained (vmcnt) + mbias visible

    for (int jt = 0; jt < NT; ++jt) {
        const int bs = jt & 1, j0 = jt * BN;
        // DMA next tile into the other buffer; in flight across this compute
        const int jn = (jt + 1 < NT) ? (jt + 1) * BN : j0;
        dma_tile(jn, bs ^ 1);

        // ---- stage 1: S^T = K*Q^T (A=Kb rows, B=Q frags), exp -> Pb ----
        #pragma unroll
        for (int nt = 0; nt < 4; ++nt) {
            const int arow = nt * 16 + m;             // arow&15 == m
            f32x4 cs = (f32x4){0.f, 0.f, 0.f, 0.f};
            #pragma unroll
            for (int kt = 0; kt < 4; ++kt) {
                bf16x8 av = *(const bf16x8*)(&Kb[bs][arow * 128 +
                               (((kt * 4 + quad) ^ m) * 8)]);
                cs = __builtin_amdgcn_mfma_f32_16x16x32_bf16(av, aq[kt], cs, 0, 0, 0);
            }
            // C layout: col = i = m (fixed), row = j = nt*16 + quad*4 + r
            const float4 m4 = *(const float4*)&mbias[j0 + nt * 16 + quad * 4];
            const float base = fi - (float)(j0 + nt * 16 + quad * 4);
            bf16x4 pv;
            #pragma unroll
            for (int r = 0; r < 4; ++r) {
                float e = __expf(cs[r] + fminf(base - (float)r, 10.f)
                                 + ((const float*)&m4)[r]);
                dsum += e;
                pv[r] = (__bf16)e;
            }
            const int irow = 16 * w + m;
            const int jc = nt * 2 + (quad >> 1);
            *(bf16x4*)(&Pb[irow * 64 + ((jc ^ (m & 7)) * 8) + (quad & 1) * 4]) = pv;
        }

        // ---- stage 2: O^T += K^T * P^T (Pb rows wave-private) ----
        const int prow = 16 * w + m;
        bf16x8 ap[2];
        #pragma unroll
        for (int k2 = 0; k2 < 2; ++k2)
            ap[k2] = *(const bf16x8*)(&Pb[prow * 64 +
                         (((k2 * 4 + quad) ^ (m & 7)) * 8)]);
        #pragma unroll
        for (int n2 = 0; n2 < 8; ++n2) {
            const int drow = n2 * 16 + m;             // drow&7 == m&7
            #pragma unroll
            for (int k2 = 0; k2 < 2; ++k2) {
                bf16x8 av = *(const bf16x8*)(&KTb[bs][drow * 64 +
                               (((k2 * 4 + quad) ^ (m & 7)) * 8)]);
                acc[n2] = __builtin_amdgcn_mfma_f32_16x16x32_bf16(av, ap[k2], acc[n2], 0, 0, 0);
            }
        }
        __syncthreads();   // next buffer's DMA drained; this buffer reusable
    }

    // ---- epilogue: O^T C-layout col = i, rows d = n2*16 + quad*4 + r ----
    dsum += __shfl_xor(dsum, 16);
    dsum += __shfl_xor(dsum, 32);
    const int i = i0 + 16 * w + m;
    const float mi = (mask[b * Tn + i] != 0) ? 1.f : 0.f;
    const float inv = mi / (dsum + EPSF);
    float* orow = out + (size_t)(b * Tn + i) * Dn;
    #pragma unroll
    for (int n2 = 0; n2 < 8; ++n2) {
        float4 o;
        o.x = acc[n2][0] * inv; o.y = acc[n2][1] * inv;
        o.z = acc[n2][2] * inv; o.w = acc[n2][3] * inv;
        *(float4*)(orow + n2 * 16 + quad * 4) = o;
    }
}

// ===================== fallback fp32 kernel (no ws) =====================
constexpr int KS = 128;
__device__ __forceinline__ int swz(int row, int c4) { return (c4 ^ ((row >> 2) & 7)); }

__global__ __launch_bounds__(256, 2)
void attn_fused(const float* __restrict__ x, const int* __restrict__ mask,
                float* __restrict__ out) {
    __shared__ float Qs[BM * KS];
    __shared__ float Ks[BN * KS];
    __shared__ float Pt[BN * BM];
    __shared__ float mks[BN];
    const int t = threadIdx.x, b = blockIdx.y, i0 = blockIdx.x * BM;
    const float* xb = x + (size_t)b * Tn * Dn;
    #pragma unroll
    for (int k = 0; k < 8; ++k) {
        int idx = t + k * 256, r = idx >> 5, c4 = idx & 31;
        float4 v = *(const float4*)(xb + (size_t)(i0 + r) * Dn + c4 * 4);
        *(float4*)(&Qs[r * KS + swz(r, c4) * 4]) = v;
    }
    const int sx = t & 15, sy = t >> 4, pc = t & 15, pr = t >> 4;
    float acc[4][8], den[4] = {0.f, 0.f, 0.f, 0.f};
    #pragma unroll
    for (int r = 0; r < 4; ++r)
        #pragma unroll
        for (int c = 0; c < 8; ++c) acc[r][c] = 0.f;
    for (int jt = 0; jt < Tn / BN; ++jt) {
        const int j0 = jt * BN;
        __syncthreads();
        #pragma unroll
        for (int k = 0; k < 8; ++k) {
            int idx = t + k * 256, r = idx >> 5, c4 = idx & 31;
            float4 v = *(const float4*)(xb + (size_t)(j0 + r) * Dn + c4 * 4);
            *(float4*)(&Ks[r * KS + swz(r, c4) * 4]) = v;
        }
        if (t < BN) mks[t] = (mask[b * Tn + j0 + t] != 0) ? 1.0f : 0.0f;
        __syncthreads();
        float s[4][4];
        #pragma unroll
        for (int r = 0; r < 4; ++r)
            #pragma unroll
            for (int c = 0; c < 4; ++c) s[r][c] = 0.f;
        #pragma unroll 4
        for (int d4 = 0; d4 < Dn / 4; ++d4) {
            float4 q[4], kk[4];
            #pragma unroll
            for (int r = 0; r < 4; ++r)
                q[r] = *(const float4*)(&Qs[(4 * sy + r) * KS + (d4 ^ (sy & 7)) * 4]);
            #pragma unroll
            for (int c = 0; c < 4; ++c)
                kk[c] = *(const float4*)(&Ks[(4 * sx + c) * KS + (d4 ^ (sx & 7)) * 4]);
            #pragma unroll
            for (int r = 0; r < 4; ++r)
                #pragma unroll
                for (int c = 0; c < 4; ++c)
                    s[r][c] += q[r].x * kk[c].x + q[r].y * kk[c].y
                             + q[r].z * kk[c].z + q[r].w * kk[c].w;
        }
        #pragma unroll
        for (int r = 0; r < 4; ++r) {
            int i = i0 + 4 * sy + r;
            #pragma unroll
            for (int c = 0; c < 4; ++c) {
                int j = j0 + 4 * sx + c, di = i - j;
                float dist = (float)(di < 10 ? di : 10);
                Pt[(4 * sx + c) * BM + (4 * sy + r)] =
                    __expf(s[r][c] + dist) * mks[4 * sx + c];
            }
        }
        __syncthreads();
        #pragma unroll 4
        for (int j = 0; j < BN; ++j) {
            float4 p4 = *(const float4*)(&Pt[j * BM + 4 * pr]);
            int sw = (j >> 2) & 7;
            float4 k0 = *(const float4*)(&Ks[j * KS + ((2 * pc)     ^ sw) * 4]);
            float4 k1 = *(const float4*)(&Ks[j * KS + ((2 * pc + 1) ^ sw) * 4]);
            float pv[4] = {p4.x, p4.y, p4.z, p4.w};
            #pragma unroll
            for (int r = 0; r < 4; ++r) {
                den[r] += pv[r];
                acc[r][0] += pv[r] * k0.x; acc[r][1] += pv[r] * k0.y;
                acc[r][2] += pv[r] * k0.z; acc[r][3] += pv[r] * k0.w;
                acc[r][4] += pv[r] * k1.x; acc[r][5] += pv[r] * k1.y;
                acc[r][6] += pv[r] * k1.z; acc[r][7] += pv[r] * k1.w;
            }
        }
    }
    const int* mrow = mask + (size_t)b * Tn + i0;
    float* ob = out + ((size_t)b * Tn + i0) * Dn;
    #pragma unroll
    for (int r = 0; r < 4; ++r) {
        int row = 4 * pr + r;
        float mi = (mrow[row] != 0) ? 1.0f : 0.0f;
        float inv = mi / (den[r] + EPSF);
        float4 o0, o1;
        o0.x = acc[r][0] * inv; o0.y = acc[r][1] * inv;
        o0.z = acc[r][2] * inv; o0.w = acc[r][3] * inv;
        o1.x = acc[r][4] * inv; o1.y = acc[r][5] * inv;
        o1.z = acc[r][6] * inv; o1.w = acc[r][7] * inv;
        *(float4*)(&ob[(size_t)row * Dn + 8 * pc    ]) = o0;
        *(float4*)(&ob[(size_t)row * Dn + 8 * pc + 4]) = o1;
    }
}

// ============================ launch ============================
extern "C" void kernel_launch(void* const* d_in, const int* in_sizes, int n_in,
                              void* d_out, int out_size, void* d_ws, size_t ws_size,
                              hipStream_t stream) {
    const float* x    = (const float*)d_in[0];
    const int*   mask = (const int*)d_in[1];
    float*       out  = (float*)d_out;
    const int nx = in_sizes[0];              // B*T*D
    const int B  = in_sizes[1] / Tn;         // 32

    const size_t need = (size_t)nx * 2 * 2;  // Xb + XbT bf16
    if (ws_size >= need) {
        __bf16* Xb  = (__bf16*)d_ws;
        __bf16* XbT = Xb + nx;
        dim3 pg(Tn / 64, B);
        prep<<<pg, 256, 0, stream>>>(x, Xb, XbT);
        attn_mfma<<<B * (Tn / BM), 256, 0, stream>>>(Xb, XbT, mask, out);
    } else {
        dim3 grid(Tn / BM, B);
        attn_fused<<<grid, 256, 0, stream>>>(x, mask, out);
    }
}